// Round 4
// baseline (691.917 us; speedup 1.0000x reference)
//
#include <hip/hip_runtime.h>
#include <math.h>

// FSQ: h = LayerNorm(x); logits = h @ W^T (n=8); q = round(4*tanh(logits))
// rows = 65536, D = 1024. Memory-bound (256 MiB read), roofline ~43 us.
//
// Fast path: all-f32, gw = gamma*W staged in LDS (32 KiB/block), TWO rows
// per wave-iteration so each ds_read_b128 of gw feeds FMAs for both rows
// (halves DS-pipe traffic to ~35 us/CU, under the 43 us HBM floor) and the
// two serial shuffle-reduce tails interleave for ILP.
//   Per lane per row: 16 x-elements, A[n] += x*gw (8 accumulators),
//   tree-reduced across 64 lanes -> f32 dot error ~1e-5, far under MARGIN.
//   mean/var f32 (E[x^2]-mu^2), tanh via f32 exp. Rows with 4*tanh within
//   MARGIN of a rounding boundary (~400 of 65536) take a fixup that
//   replicates numpy-f32 semantics bit-exactly, re-reading the row from
//   global x (same bits the fast path loaded):
//   mean/var : pairwise sum, 128-blocks, 8 scalar accumulators, fixed trees
//   einsum   : SSE3 baseline c_einsum dot — width 4, mul+add (no fma),
//              k-unroll x4 serpentine (j=3..0), hadd finale (v0+v1)+(v2+v3)
//   tanh     : f64 tanh of the exact logit32
//
// Rev history:
//  - r0 (920 us): fp64 truth + reg W/gamma/beta spilled (1.24 GB FETCH).
//  - r2 (~157 us): f32 + reg gw, no spill, but 128 VGPR gw -> 2 waves/SIMD,
//    latency-bound on the per-row serial shuffle tail.
//  - r3 (365 us): gw->LDS + __launch_bounds__(256,4): allocator overshot the
//    4-wave floor, targeted 64 VGPR (8 waves) and spilled ~11 regs/lane ->
//    175 MB scratch WRITE + 248 MB extra FETCH. Lesson: pin waves/EU max.
//  - this rev: amdgpu_waves_per_eu(4,4) pins the 128-VGPR budget (no
//    spill-for-occupancy), 2 rows/iter, no sw prefetch (TLP covers HBM lat).

#define NROWS 65536
#define DMODEL 1024
#define NL 8
#define NBLOCKS 1024
#define TPB 256
#define NWAVES (NBLOCKS * TPB / 64)   // 4096 -> 16 rows/wave, 8 iter x 2 rows
#define MARGIN 2e-3f

// Reduce-scatter 8 doubles across 64 lanes.
// After: every lane holds total of a[n] with n = 4*bit5 + 2*bit4 + 1*bit3.
__device__ __forceinline__ double reduce_scatter8_f64(double a[8], int lane) {
#pragma unroll
    for (int i = 0; i < 4; ++i) {
        double snd = (lane & 32) ? a[i] : a[i + 4];
        double rcv = __shfl_xor(snd, 32, 64);
        double kp  = (lane & 32) ? a[i + 4] : a[i];
        a[i] = kp + rcv;
    }
#pragma unroll
    for (int i = 0; i < 2; ++i) {
        double snd = (lane & 16) ? a[i] : a[i + 2];
        double rcv = __shfl_xor(snd, 16, 64);
        double kp  = (lane & 16) ? a[i + 2] : a[i];
        a[i] = kp + rcv;
    }
    {
        double snd = (lane & 8) ? a[0] : a[1];
        double rcv = __shfl_xor(snd, 8, 64);
        double kp  = (lane & 8) ? a[1] : a[0];
        a[0] = kp + rcv;
    }
    double v = a[0];
    v += __shfl_xor(v, 4, 64);
    v += __shfl_xor(v, 2, 64);
    v += __shfl_xor(v, 1, 64);
    return v;
}

// Same, f32 (fast path).
__device__ __forceinline__ float reduce_scatter8_f32(float a[8], int lane) {
#pragma unroll
    for (int i = 0; i < 4; ++i) {
        float snd = (lane & 32) ? a[i] : a[i + 4];
        float rcv = __shfl_xor(snd, 32, 64);
        float kp  = (lane & 32) ? a[i + 4] : a[i];
        a[i] = kp + rcv;
    }
#pragma unroll
    for (int i = 0; i < 2; ++i) {
        float snd = (lane & 16) ? a[i] : a[i + 2];
        float rcv = __shfl_xor(snd, 16, 64);
        float kp  = (lane & 16) ? a[i + 2] : a[i];
        a[i] = kp + rcv;
    }
    {
        float snd = (lane & 8) ? a[0] : a[1];
        float rcv = __shfl_xor(snd, 8, 64);
        float kp  = (lane & 8) ? a[1] : a[0];
        a[0] = kp + rcv;
    }
    float v = a[0];
    v += __shfl_xor(v, 4, 64);
    v += __shfl_xor(v, 2, 64);
    v += __shfl_xor(v, 1, 64);
    return v;
}

// numpy pairwise_sum over 1024 contiguous f32 (global), bit-exact:
// 4 recursion levels -> 8 blocks of 128; per block 8 accumulators r[j],
// r[j] = x[j]; r[j] += x[8i+j] (i=1..15); tree ((r0+r1)+(r2+r3))+((r4+r5)+(r6+r7));
// block sums combined ((s0+s1)+(s2+s3))+((s4+s5)+(s6+s7)).
// Lane L = 8*b + j owns accumulator j of block b; butterfly masks 1,2,4,8,16,32
// reproduce both trees bit-exactly (fl(a+b)==fl(b+a) => all lanes identical).
__device__ __forceinline__ float np_pairwise_sum_sq(const float* xr, int lane,
                                                    float mu, int do_sq) {
    const int b = lane >> 3, j = lane & 7;
    const float* xb = xr + 128 * b;
    float r;
    if (do_sq) {
        float t = __fsub_rn(xb[j], mu);
        r = __fmul_rn(t, t);
        for (int i = 8; i < 128; i += 8) {
            float u = __fsub_rn(xb[i + j], mu);
            r = __fadd_rn(r, __fmul_rn(u, u));
        }
    } else {
        r = xb[j];
        for (int i = 8; i < 128; i += 8)
            r = __fadd_rn(r, xb[i + j]);
    }
    r = __fadd_rn(r, __shfl_xor(r, 1, 64));
    r = __fadd_rn(r, __shfl_xor(r, 2, 64));
    r = __fadd_rn(r, __shfl_xor(r, 4, 64));
    r = __fadd_rn(r, __shfl_xor(r, 8, 64));
    r = __fadd_rn(r, __shfl_xor(r, 16, 64));
    r = __fadd_rn(r, __shfl_xor(r, 32, 64));
    return r;   // identical on all 64 lanes
}

// Per-row epilogue: LN stats -> logit -> 4*tanh -> round (or bit-exact fixup).
__device__ __forceinline__ void finish_row(
    int r, int lane, int nidx, float s, float qq, float S1,
    float S2f, float S3f,
    const float* __restrict__ x, const float* __restrict__ gamma,
    const float* __restrict__ beta, const float* __restrict__ W,
    float* __restrict__ out)
{
    const float mu    = s * (1.0f / 1024.0f);
    const float var   = fmaf(-mu, mu, qq * (1.0f / 1024.0f));
    const float rstd  = rsqrtf(var + 1e-5f);
    const float logit = fmaf(rstd, fmaf(-mu, S2f, S1), S3f);

    // fast f32 tanh: t = (1-e)/(1+e), e = exp(-2|logit|); abs err ~1e-6
    const float af  = fabsf(logit);
    const float e   = __expf(-2.0f * af);
    const float t   = __fdividef(1.0f - e, 1.0f + e);
    const float b4  = copysignf(4.0f * t, logit);

    const float fr    = b4 - floorf(b4);
    const float delta = fabsf(fr - 0.5f);
    const unsigned long long near_mask = __ballot(delta < MARGIN);

    if (near_mask == 0ull) {
        if ((lane & 7) == 0)
            out[(size_t)r * NL + nidx] = rintf(b4);
    } else {
        // ======== fixup: bit-exact numpy-f32 replication ========
        const float* xr = x + (size_t)r * DMODEL;

        const float sum32 = np_pairwise_sum_sq(xr, lane, 0.0f, 0);
        const float mu32  = __fmul_rn(sum32, 0.0009765625f);
        const float sq32  = np_pairwise_sum_sq(xr, lane, mu32, 1);
        const float var32 = __fmul_rn(sq32, 0.0009765625f);
        const float rstd32 = __fdiv_rn(1.0f, __fsqrt_rn(__fadd_rn(var32, 1e-5f)));

        // einsum dot, SSE3 baseline c_einsum: width 4, no fma,
        // 16 elems/iter, serpentine j=3..0, finale (v0+v1)+(v2+v3).
        if (lane < 32) {
            const int n = lane >> 2, v = lane & 3;
            const float* Wn = W + n * DMODEL;
            float vacc = 0.0f;
            for (int i = 0; i < DMODEL; i += 16) {
#pragma unroll
                for (int j = 3; j >= 0; --j) {
                    const int e2 = i + 4 * j + v;
                    const float t1 = __fsub_rn(xr[e2], mu32);
                    const float t2 = __fmul_rn(t1, rstd32);
                    const float t3 = __fmul_rn(t2, gamma[e2]);
                    const float h  = __fadd_rn(t3, beta[e2]);
                    vacc = __fadd_rn(__fmul_rn(h, Wn[e2]), vacc);
                }
            }
            float s01 = __fadd_rn(vacc, __shfl_xor(vacc, 1, 64));
            float lg  = __fadd_rn(s01,  __shfl_xor(s01, 2, 64));
            if (v == 0) {
                const double y = 4.0 * tanh((double)lg);
                out[(size_t)r * NL + n] = (float)rint(y);
            }
        }
    }
}

__global__ __launch_bounds__(TPB) __attribute__((amdgpu_waves_per_eu(4, 4)))
void fsq_kernel(const float* __restrict__ x,
                const float* __restrict__ gamma,
                const float* __restrict__ beta,
                const float* __restrict__ W,
                float* __restrict__ out)
{
    __shared__ float gw_lds[NL][DMODEL];   // 32 KiB: gamma*W, block-shared

    const int lane = threadIdx.x & 63;
    const int wv   = threadIdx.x >> 6;
    const int wid  = (blockIdx.x * TPB + threadIdx.x) >> 6;

    // output column this lane's reduce-scatter group owns
    const int nidx = ((lane >> 5) & 1) * 4 + ((lane >> 4) & 1) * 2 + ((lane >> 3) & 1);

    // ---- prologue: gw = gamma*W into LDS; S2/S3 (f64, per wave) ----
    float S2f, S3f;
    {
        double s2p[NL], s3p[NL];
#pragma unroll
        for (int n = 0; n < NL; ++n) { s2p[n] = 0.0; s3p[n] = 0.0; }
#pragma unroll
        for (int c = 0; c < 4; ++c) {
            const int d = c * 256 + lane * 4;
            const float4 g = *reinterpret_cast<const float4*>(gamma + d);
            const float4 b = *reinterpret_cast<const float4*>(beta + d);
#pragma unroll
            for (int n = 0; n < NL; ++n) {
                const float4 w = *reinterpret_cast<const float4*>(W + n * DMODEL + d);
                s2p[n] = fma((double)g.x, (double)w.x, s2p[n]);
                s2p[n] = fma((double)g.y, (double)w.y, s2p[n]);
                s2p[n] = fma((double)g.z, (double)w.z, s2p[n]);
                s2p[n] = fma((double)g.w, (double)w.w, s2p[n]);
                s3p[n] = fma((double)b.x, (double)w.x, s3p[n]);
                s3p[n] = fma((double)b.y, (double)w.y, s3p[n]);
                s3p[n] = fma((double)b.z, (double)w.z, s3p[n]);
                s3p[n] = fma((double)b.w, (double)w.w, s3p[n]);
                if (wv == 0)
                    *reinterpret_cast<float4*>(&gw_lds[n][d]) =
                        make_float4(g.x * w.x, g.y * w.y, g.z * w.z, g.w * w.w);
            }
        }
        S2f = (float)reduce_scatter8_f64(s2p, lane);
        S3f = (float)reduce_scatter8_f64(s3p, lane);
    }
    __syncthreads();

    // ------------- row loop: 2 rows per iteration, shared gw reads -------------
    for (int r = wid; r < NROWS; r += 2 * NWAVES) {
        const int rB = r + NWAVES;   // always < NROWS (NROWS = 16*NWAVES)

        float4 xa[4], ya[4];
#pragma unroll
        for (int c = 0; c < 4; ++c) {
            xa[c] = *reinterpret_cast<const float4*>(x + (size_t)r  * DMODEL + c * 256 + lane * 4);
            ya[c] = *reinterpret_cast<const float4*>(x + (size_t)rB * DMODEL + c * 256 + lane * 4);
        }

        float sA = 0.0f, qqA = 0.0f, sB = 0.0f, qqB = 0.0f;
        float A[NL], Bv[NL];
#pragma unroll
        for (int n = 0; n < NL; ++n) { A[n] = 0.0f; Bv[n] = 0.0f; }

#pragma unroll
        for (int c = 0; c < 4; ++c) {
            const int d = c * 256 + lane * 4;
            const float a0 = xa[c].x, a1 = xa[c].y, a2 = xa[c].z, a3 = xa[c].w;
            const float b0 = ya[c].x, b1 = ya[c].y, b2 = ya[c].z, b3 = ya[c].w;
            sA += a0 + a1 + a2 + a3;
            sB += b0 + b1 + b2 + b3;
            qqA = fmaf(a0, a0, qqA); qqA = fmaf(a1, a1, qqA);
            qqA = fmaf(a2, a2, qqA); qqA = fmaf(a3, a3, qqA);
            qqB = fmaf(b0, b0, qqB); qqB = fmaf(b1, b1, qqB);
            qqB = fmaf(b2, b2, qqB); qqB = fmaf(b3, b3, qqB);
#pragma unroll
            for (int n = 0; n < NL; ++n) {
                const float4 w4 = *reinterpret_cast<const float4*>(&gw_lds[n][d]);
                A[n]  = fmaf(a0, w4.x, A[n]);
                A[n]  = fmaf(a1, w4.y, A[n]);
                A[n]  = fmaf(a2, w4.z, A[n]);
                A[n]  = fmaf(a3, w4.w, A[n]);
                Bv[n] = fmaf(b0, w4.x, Bv[n]);
                Bv[n] = fmaf(b1, w4.y, Bv[n]);
                Bv[n] = fmaf(b2, w4.z, Bv[n]);
                Bv[n] = fmaf(b3, w4.w, Bv[n]);
            }
        }

        // interleaved reductions: two independent chains hide shuffle latency
#pragma unroll
        for (int m = 32; m >= 1; m >>= 1) {
            sA  += __shfl_xor(sA,  m, 64);
            sB  += __shfl_xor(sB,  m, 64);
            qqA += __shfl_xor(qqA, m, 64);
            qqB += __shfl_xor(qqB, m, 64);
        }
        const float S1A = reduce_scatter8_f32(A,  lane);
        const float S1B = reduce_scatter8_f32(Bv, lane);

        finish_row(r,  lane, nidx, sA, qqA, S1A, S2f, S3f, x, gamma, beta, W, out);
        finish_row(rB, lane, nidx, sB, qqB, S1B, S2f, S3f, x, gamma, beta, W, out);
    }
}

extern "C" void kernel_launch(void* const* d_in, const int* in_sizes, int n_in,
                              void* d_out, int out_size, void* d_ws, size_t ws_size,
                              hipStream_t stream) {
    const float* regrs = (const float*)d_in[0];
    const float* gamma = (const float*)d_in[1];
    const float* beta  = (const float*)d_in[2];
    const float* W     = (const float*)d_in[3];
    float* out = (float*)d_out;
    (void)in_sizes; (void)n_in; (void)out_size; (void)d_ws; (void)ws_size;

    fsq_kernel<<<NBLOCKS, TPB, 0, stream>>>(regrs, gamma, beta, W, out);
}

// Round 5
// 402.475 us; speedup vs baseline: 1.7192x; 1.7192x over previous
//
#include <hip/hip_runtime.h>
#include <math.h>

// FSQ: h = LayerNorm(x); logits = h @ W^T (n=8); q = round(4*tanh(logits))
// rows = 65536, D = 1024. Memory-bound (256 MiB read), roofline ~43 us.
//
// Fast path: all-f32, register-resident gw = gamma*W (128 VGPR).
//   Per lane: 16 x-elements, A[n] += x*gw (8 accumulators), tree-reduced
//   across 64 lanes -> f32 dot error ~1e-5, far under MARGIN. mean/var f32
//   (E[x^2]-mu^2), tanh via f32 exp. Rows with 4*tanh within MARGIN of a
//   rounding boundary (~400 of 65536) take a fixup that replicates numpy-f32
//   semantics bit-exactly (LDS-staged row):
//   mean/var : pairwise sum, 128-blocks, 8 scalar accumulators, fixed trees
//   einsum   : SSE3 baseline c_einsum dot — width 4, mul+add (no fma),
//              k-unroll x4 serpentine (j=3..0), hadd finale (v0+v1)+(v2+v3)
//   tanh     : f64 tanh of the exact logit32
//
// Rev history:
//  - r0 (920 us): fp64 truth + reg W/gamma/beta spilled (1.24 GB FETCH).
//  - r2 (157 us): this structure at NBLOCKS=512: VGPR=128, no spill, but
//    grid-limited to 2 blocks/CU (8 waves/CU, 20% occ) -> latency-bound.
//  - r3/r4 (365/438 us): gw->LDS + waves-per-EU hints: allocator targeted
//    the doubled occupancy tier (64 VGPR) and spilled 175-239 MB scratch.
//    Lesson: launch_bounds(256,2) + this structure is the known-good
//    regalloc; scale occupancy with GRID, not allocator hints.
//  - this rev: identical kernel, NBLOCKS 512 -> 1024 (4 blocks/CU = the
//    VGPR-cap occupancy, 16 waves/CU), 16 rows/wave.

#define NROWS 65536
#define DMODEL 1024
#define NL 8
#define NBLOCKS 1024
#define TPB 256
#define NWAVES (NBLOCKS * TPB / 64)   // 4096 -> 16 rows/wave
#define MARGIN 2e-3f

// Reduce-scatter 8 doubles across 64 lanes.
// After: every lane holds total of a[n] with n = 4*bit5 + 2*bit4 + 1*bit3.
__device__ __forceinline__ double reduce_scatter8_f64(double a[8], int lane) {
#pragma unroll
    for (int i = 0; i < 4; ++i) {
        double snd = (lane & 32) ? a[i] : a[i + 4];
        double rcv = __shfl_xor(snd, 32, 64);
        double kp  = (lane & 32) ? a[i + 4] : a[i];
        a[i] = kp + rcv;
    }
#pragma unroll
    for (int i = 0; i < 2; ++i) {
        double snd = (lane & 16) ? a[i] : a[i + 2];
        double rcv = __shfl_xor(snd, 16, 64);
        double kp  = (lane & 16) ? a[i + 2] : a[i];
        a[i] = kp + rcv;
    }
    {
        double snd = (lane & 8) ? a[0] : a[1];
        double rcv = __shfl_xor(snd, 8, 64);
        double kp  = (lane & 8) ? a[1] : a[0];
        a[0] = kp + rcv;
    }
    double v = a[0];
    v += __shfl_xor(v, 4, 64);
    v += __shfl_xor(v, 2, 64);
    v += __shfl_xor(v, 1, 64);
    return v;
}

// Same, f32 (fast path).
__device__ __forceinline__ float reduce_scatter8_f32(float a[8], int lane) {
#pragma unroll
    for (int i = 0; i < 4; ++i) {
        float snd = (lane & 32) ? a[i] : a[i + 4];
        float rcv = __shfl_xor(snd, 32, 64);
        float kp  = (lane & 32) ? a[i + 4] : a[i];
        a[i] = kp + rcv;
    }
#pragma unroll
    for (int i = 0; i < 2; ++i) {
        float snd = (lane & 16) ? a[i] : a[i + 2];
        float rcv = __shfl_xor(snd, 16, 64);
        float kp  = (lane & 16) ? a[i + 2] : a[i];
        a[i] = kp + rcv;
    }
    {
        float snd = (lane & 8) ? a[0] : a[1];
        float rcv = __shfl_xor(snd, 8, 64);
        float kp  = (lane & 8) ? a[1] : a[0];
        a[0] = kp + rcv;
    }
    float v = a[0];
    v += __shfl_xor(v, 4, 64);
    v += __shfl_xor(v, 2, 64);
    v += __shfl_xor(v, 1, 64);
    return v;
}

// numpy pairwise_sum over 1024 contiguous f32 in LDS, bit-exact:
// 4 recursion levels -> 8 blocks of 128; per block 8 accumulators r[j],
// r[j] = x[j]; r[j] += x[8i+j] (i=1..15); tree ((r0+r1)+(r2+r3))+((r4+r5)+(r6+r7));
// block sums combined ((s0+s1)+(s2+s3))+((s4+s5)+(s6+s7)).
// Lane L = 8*b + j owns accumulator j of block b; butterfly masks 1,2,4,8,16,32
// reproduce both trees bit-exactly (fl(a+b)==fl(b+a) => all lanes identical).
__device__ __forceinline__ float np_pairwise_sum_sq(const float* xr, int lane,
                                                    float mu, int do_sq) {
    const int b = lane >> 3, j = lane & 7;
    const float* xb = xr + 128 * b;
    float r;
    if (do_sq) {
        float t = __fsub_rn(xb[j], mu);
        r = __fmul_rn(t, t);
        for (int i = 8; i < 128; i += 8) {
            float u = __fsub_rn(xb[i + j], mu);
            r = __fadd_rn(r, __fmul_rn(u, u));
        }
    } else {
        r = xb[j];
        for (int i = 8; i < 128; i += 8)
            r = __fadd_rn(r, xb[i + j]);
    }
    r = __fadd_rn(r, __shfl_xor(r, 1, 64));
    r = __fadd_rn(r, __shfl_xor(r, 2, 64));
    r = __fadd_rn(r, __shfl_xor(r, 4, 64));
    r = __fadd_rn(r, __shfl_xor(r, 8, 64));
    r = __fadd_rn(r, __shfl_xor(r, 16, 64));
    r = __fadd_rn(r, __shfl_xor(r, 32, 64));
    return r;   // identical on all 64 lanes
}

__global__ __launch_bounds__(TPB, 2)
void fsq_kernel(const float* __restrict__ x,
                const float* __restrict__ gamma,
                const float* __restrict__ beta,
                const float* __restrict__ W,
                float* __restrict__ out)
{
    __shared__ float xbuf[TPB / 64][DMODEL];   // 16 KiB: staged x row per wave

    const int lane = threadIdx.x & 63;
    const int wv   = threadIdx.x >> 6;
    const int wid  = (blockIdx.x * TPB + threadIdx.x) >> 6;

    // output column this lane's reduce-scatter group owns
    const int nidx = ((lane >> 5) & 1) * 4 + ((lane >> 4) & 1) * 2 + ((lane >> 3) & 1);

    // ---- prologue: gw = gamma*W register-resident (f32); S2/S3 in f64 ----
    float4 gw[NL][4];
    float S2f, S3f;
    {
        double s2p[NL], s3p[NL];
#pragma unroll
        for (int n = 0; n < NL; ++n) { s2p[n] = 0.0; s3p[n] = 0.0; }
#pragma unroll
        for (int c = 0; c < 4; ++c) {
            const int d = c * 256 + lane * 4;
            const float4 g = *reinterpret_cast<const float4*>(gamma + d);
            const float4 b = *reinterpret_cast<const float4*>(beta + d);
#pragma unroll
            for (int n = 0; n < NL; ++n) {
                const float4 w = *reinterpret_cast<const float4*>(W + n * DMODEL + d);
                s2p[n] = fma((double)g.x, (double)w.x, s2p[n]);
                s2p[n] = fma((double)g.y, (double)w.y, s2p[n]);
                s2p[n] = fma((double)g.z, (double)w.z, s2p[n]);
                s2p[n] = fma((double)g.w, (double)w.w, s2p[n]);
                s3p[n] = fma((double)b.x, (double)w.x, s3p[n]);
                s3p[n] = fma((double)b.y, (double)w.y, s3p[n]);
                s3p[n] = fma((double)b.z, (double)w.z, s3p[n]);
                s3p[n] = fma((double)b.w, (double)w.w, s3p[n]);
                gw[n][c] = make_float4(g.x * w.x, g.y * w.y, g.z * w.z, g.w * w.w);
            }
        }
        S2f = (float)reduce_scatter8_f64(s2p, lane);
        S3f = (float)reduce_scatter8_f64(s3p, lane);
    }

    // ---------------- row loop with x prefetch ----------------
    int r = wid;
    float4 xa[4];
#pragma unroll
    for (int c = 0; c < 4; ++c)
        xa[c] = *reinterpret_cast<const float4*>(x + (size_t)r * DMODEL + c * 256 + lane * 4);

    while (r < NROWS) {
        const int rn = r + NWAVES;
        const int rp = (rn < NROWS) ? rn : r;
        float4 xb[4];
#pragma unroll
        for (int c = 0; c < 4; ++c)
            xb[c] = *reinterpret_cast<const float4*>(x + (size_t)rp * DMODEL + c * 256 + lane * 4);

        // --- per-lane accumulate (all f32; error << MARGIN, see header) ---
        float s = 0.0f, qq = 0.0f;
        float A[NL];
#pragma unroll
        for (int n = 0; n < NL; ++n) A[n] = 0.0f;

#pragma unroll
        for (int c = 0; c < 4; ++c) {
            const float x0 = xa[c].x, x1 = xa[c].y, x2 = xa[c].z, x3 = xa[c].w;
            s += x0 + x1 + x2 + x3;
            qq = fmaf(x0, x0, qq); qq = fmaf(x1, x1, qq);
            qq = fmaf(x2, x2, qq); qq = fmaf(x3, x3, qq);
#pragma unroll
            for (int n = 0; n < NL; ++n) {
                A[n] = fmaf(x0, gw[n][c].x, A[n]);
                A[n] = fmaf(x1, gw[n][c].y, A[n]);
                A[n] = fmaf(x2, gw[n][c].z, A[n]);
                A[n] = fmaf(x3, gw[n][c].w, A[n]);
            }
        }

#pragma unroll
        for (int m = 32; m >= 1; m >>= 1) {
            s  += __shfl_xor(s,  m, 64);
            qq += __shfl_xor(qq, m, 64);
        }
        const float S1 = reduce_scatter8_f32(A, lane);

        const float mu    = s * (1.0f / 1024.0f);
        const float var   = fmaf(-mu, mu, qq * (1.0f / 1024.0f));
        const float rstd  = rsqrtf(var + 1e-5f);
        const float logit = fmaf(rstd, fmaf(-mu, S2f, S1), S3f);

        // fast f32 tanh: t = (1-e)/(1+e), e = exp(-2|logit|); abs err ~1e-6
        const float af  = fabsf(logit);
        const float e   = __expf(-2.0f * af);
        const float t   = __fdividef(1.0f - e, 1.0f + e);
        const float b4  = copysignf(4.0f * t, logit);

        const float fr    = b4 - floorf(b4);
        const float delta = fabsf(fr - 0.5f);
        const unsigned long long near_mask = __ballot(delta < MARGIN);

        if (near_mask == 0ull) {
            if ((lane & 7) == 0)
                out[(size_t)r * NL + nidx] = rintf(b4);
        } else {
            // ======== fixup: bit-exact numpy-f32 replication ========
            float* xr = &xbuf[wv][0];
#pragma unroll
            for (int c = 0; c < 4; ++c)
                *reinterpret_cast<float4*>(xr + c * 256 + lane * 4) = xa[c];
            __threadfence_block();   // drain ds_writes before cross-lane reads

            // mean: pairwise f32, /1024 exact
            const float sum32 = np_pairwise_sum_sq(xr, lane, 0.0f, 0);
            const float mu32  = __fmul_rn(sum32, 0.0009765625f);
            // var: pairwise f32 over (x-mu)^2, /1024 exact
            const float sq32  = np_pairwise_sum_sq(xr, lane, mu32, 1);
            const float var32 = __fmul_rn(sq32, 0.0009765625f);
            const float rstd32 = __fdiv_rn(1.0f, __fsqrt_rn(__fadd_rn(var32, 1e-5f)));

            // einsum dot, SSE3 baseline c_einsum: width 4, no fma,
            // 16 elems/iter, serpentine j=3..0, finale (v0+v1)+(v2+v3).
            if (lane < 32) {
                const int n = lane >> 2, v = lane & 3;
                const float* Wn = W + n * DMODEL;
                float vacc = 0.0f;
                for (int i = 0; i < DMODEL; i += 16) {
#pragma unroll
                    for (int j = 3; j >= 0; --j) {
                        const int e2 = i + 4 * j + v;
                        const float t1 = __fsub_rn(xr[e2], mu32);
                        const float t2 = __fmul_rn(t1, rstd32);
                        const float t3 = __fmul_rn(t2, gamma[e2]);
                        const float h  = __fadd_rn(t3, beta[e2]);
                        vacc = __fadd_rn(__fmul_rn(h, Wn[e2]), vacc);
                    }
                }
                float s01 = __fadd_rn(vacc, __shfl_xor(vacc, 1, 64));
                float lg  = __fadd_rn(s01,  __shfl_xor(s01, 2, 64));
                if (v == 0) {
                    const double y = 4.0 * tanh((double)lg);
                    out[(size_t)r * NL + n] = (float)rint(y);
                }
            }
        }

#pragma unroll
        for (int c = 0; c < 4; ++c) xa[c] = xb[c];
        r = rn;
    }
}

extern "C" void kernel_launch(void* const* d_in, const int* in_sizes, int n_in,
                              void* d_out, int out_size, void* d_ws, size_t ws_size,
                              hipStream_t stream) {
    const float* regrs = (const float*)d_in[0];
    const float* gamma = (const float*)d_in[1];
    const float* beta  = (const float*)d_in[2];
    const float* W     = (const float*)d_in[3];
    float* out = (float*)d_out;
    (void)in_sizes; (void)n_in; (void)out_size; (void)d_ws; (void)ws_size;

    fsq_kernel<<<NBLOCKS, TPB, 0, stream>>>(regrs, gamma, beta, W, out);
}

// Round 6
// 401.335 us; speedup vs baseline: 1.7240x; 1.0028x over previous
//
#include <hip/hip_runtime.h>
#include <math.h>

// FSQ: h = LayerNorm(x); logits = h @ W^T (n=8); q = round(4*tanh(logits))
// rows = 65536, D = 1024. Memory-bound (256 MiB read), roofline ~43 us.
//
// Fast path: all-f32, register-resident gw = gamma*W (128 VGPR).
//   Per lane: 16 x-elements, A[n] += x*gw (8 accumulators), tree-reduced
//   across 64 lanes -> f32 dot error ~1e-5, far under MARGIN. mean/var f32
//   (E[x^2]-mu^2), tanh via f32 exp. Rows with 4*tanh within MARGIN of a
//   rounding boundary (~800 of 65536) take a fixup that replicates numpy-f32
//   semantics bit-exactly (LDS-staged row).
//
// ROW MAPPING (this rev's only change): block b owns rows [b*64, b*64+64);
// wave wv processes rows b*64+wv, +4, ... So per iteration the block streams
// a contiguous 16 KB chunk and the whole block is one sequential 256 KB
// stream (fill-like DRAM locality, 1024 streams).
//
// Rev history:
//  - r0 (920 us): fp64 truth + reg W/gamma/beta spilled (1.24 GB FETCH).
//  - r2 (157 us): f32 + reg gw at 512 blocks, no spill, 1.76 TB/s.
//  - r3/r4 (365/438 us): gw->LDS + waves-per-EU hints -> allocator spilled.
//  - r5 (157 us): r2 structure at 1024 blocks: 2x occupancy, SAME time ->
//    NOT latency-bound; shared-resource cap. All family members plateau at
//    ~1.8 TB/s. Theory: r += NWAVES mapping = 4096 streams jumping 16 MB
//    every 4 KB row -> every row is a DRAM page-activate (and TLB miss);
//    harness fills (long sequential streams) hit 6.6 TB/s on same chip.
//  - this rev: block-contiguous row mapping, compute byte-identical.

#define NROWS 65536
#define DMODEL 1024
#define NL 8
#define NBLOCKS 1024
#define TPB 256
#define ROWS_PER_BLOCK 64            // NROWS / NBLOCKS
#define ROWS_PER_WAVE 16             // ROWS_PER_BLOCK / 4 waves
#define MARGIN 2e-3f

// Reduce-scatter 8 doubles across 64 lanes.
// After: every lane holds total of a[n] with n = 4*bit5 + 2*bit4 + 1*bit3.
__device__ __forceinline__ double reduce_scatter8_f64(double a[8], int lane) {
#pragma unroll
    for (int i = 0; i < 4; ++i) {
        double snd = (lane & 32) ? a[i] : a[i + 4];
        double rcv = __shfl_xor(snd, 32, 64);
        double kp  = (lane & 32) ? a[i + 4] : a[i];
        a[i] = kp + rcv;
    }
#pragma unroll
    for (int i = 0; i < 2; ++i) {
        double snd = (lane & 16) ? a[i] : a[i + 2];
        double rcv = __shfl_xor(snd, 16, 64);
        double kp  = (lane & 16) ? a[i + 2] : a[i];
        a[i] = kp + rcv;
    }
    {
        double snd = (lane & 8) ? a[0] : a[1];
        double rcv = __shfl_xor(snd, 8, 64);
        double kp  = (lane & 8) ? a[1] : a[0];
        a[0] = kp + rcv;
    }
    double v = a[0];
    v += __shfl_xor(v, 4, 64);
    v += __shfl_xor(v, 2, 64);
    v += __shfl_xor(v, 1, 64);
    return v;
}

// Same, f32 (fast path).
__device__ __forceinline__ float reduce_scatter8_f32(float a[8], int lane) {
#pragma unroll
    for (int i = 0; i < 4; ++i) {
        float snd = (lane & 32) ? a[i] : a[i + 4];
        float rcv = __shfl_xor(snd, 32, 64);
        float kp  = (lane & 32) ? a[i + 4] : a[i];
        a[i] = kp + rcv;
    }
#pragma unroll
    for (int i = 0; i < 2; ++i) {
        float snd = (lane & 16) ? a[i] : a[i + 2];
        float rcv = __shfl_xor(snd, 16, 64);
        float kp  = (lane & 16) ? a[i + 2] : a[i];
        a[i] = kp + rcv;
    }
    {
        float snd = (lane & 8) ? a[0] : a[1];
        float rcv = __shfl_xor(snd, 8, 64);
        float kp  = (lane & 8) ? a[1] : a[0];
        a[0] = kp + rcv;
    }
    float v = a[0];
    v += __shfl_xor(v, 4, 64);
    v += __shfl_xor(v, 2, 64);
    v += __shfl_xor(v, 1, 64);
    return v;
}

// numpy pairwise_sum over 1024 contiguous f32 in LDS, bit-exact:
// 4 recursion levels -> 8 blocks of 128; per block 8 accumulators r[j],
// r[j] = x[j]; r[j] += x[8i+j] (i=1..15); tree ((r0+r1)+(r2+r3))+((r4+r5)+(r6+r7));
// block sums combined ((s0+s1)+(s2+s3))+((s4+s5)+(s6+s7)).
// Lane L = 8*b + j owns accumulator j of block b; butterfly masks 1,2,4,8,16,32
// reproduce both trees bit-exactly (fl(a+b)==fl(b+a) => all lanes identical).
__device__ __forceinline__ float np_pairwise_sum_sq(const float* xr, int lane,
                                                    float mu, int do_sq) {
    const int b = lane >> 3, j = lane & 7;
    const float* xb = xr + 128 * b;
    float r;
    if (do_sq) {
        float t = __fsub_rn(xb[j], mu);
        r = __fmul_rn(t, t);
        for (int i = 8; i < 128; i += 8) {
            float u = __fsub_rn(xb[i + j], mu);
            r = __fadd_rn(r, __fmul_rn(u, u));
        }
    } else {
        r = xb[j];
        for (int i = 8; i < 128; i += 8)
            r = __fadd_rn(r, xb[i + j]);
    }
    r = __fadd_rn(r, __shfl_xor(r, 1, 64));
    r = __fadd_rn(r, __shfl_xor(r, 2, 64));
    r = __fadd_rn(r, __shfl_xor(r, 4, 64));
    r = __fadd_rn(r, __shfl_xor(r, 8, 64));
    r = __fadd_rn(r, __shfl_xor(r, 16, 64));
    r = __fadd_rn(r, __shfl_xor(r, 32, 64));
    return r;   // identical on all 64 lanes
}

__global__ __launch_bounds__(TPB, 2)
void fsq_kernel(const float* __restrict__ x,
                const float* __restrict__ gamma,
                const float* __restrict__ beta,
                const float* __restrict__ W,
                float* __restrict__ out)
{
    __shared__ float xbuf[TPB / 64][DMODEL];   // 16 KiB: staged x row per wave

    const int lane = threadIdx.x & 63;
    const int wv   = threadIdx.x >> 6;

    // output column this lane's reduce-scatter group owns
    const int nidx = ((lane >> 5) & 1) * 4 + ((lane >> 4) & 1) * 2 + ((lane >> 3) & 1);

    // ---- prologue: gw = gamma*W register-resident (f32); S2/S3 in f64 ----
    float4 gw[NL][4];
    float S2f, S3f;
    {
        double s2p[NL], s3p[NL];
#pragma unroll
        for (int n = 0; n < NL; ++n) { s2p[n] = 0.0; s3p[n] = 0.0; }
#pragma unroll
        for (int c = 0; c < 4; ++c) {
            const int d = c * 256 + lane * 4;
            const float4 g = *reinterpret_cast<const float4*>(gamma + d);
            const float4 b = *reinterpret_cast<const float4*>(beta + d);
#pragma unroll
            for (int n = 0; n < NL; ++n) {
                const float4 w = *reinterpret_cast<const float4*>(W + n * DMODEL + d);
                s2p[n] = fma((double)g.x, (double)w.x, s2p[n]);
                s2p[n] = fma((double)g.y, (double)w.y, s2p[n]);
                s2p[n] = fma((double)g.z, (double)w.z, s2p[n]);
                s2p[n] = fma((double)g.w, (double)w.w, s2p[n]);
                s3p[n] = fma((double)b.x, (double)w.x, s3p[n]);
                s3p[n] = fma((double)b.y, (double)w.y, s3p[n]);
                s3p[n] = fma((double)b.z, (double)w.z, s3p[n]);
                s3p[n] = fma((double)b.w, (double)w.w, s3p[n]);
                gw[n][c] = make_float4(g.x * w.x, g.y * w.y, g.z * w.z, g.w * w.w);
            }
        }
        S2f = (float)reduce_scatter8_f64(s2p, lane);
        S3f = (float)reduce_scatter8_f64(s3p, lane);
    }

    // ------- row loop: block-contiguous rows, 4-wave interleave, prefetch -------
    int r = blockIdx.x * ROWS_PER_BLOCK + wv;   // rows r, r+4, ..., r+60
    float4 xa[4];
#pragma unroll
    for (int c = 0; c < 4; ++c)
        xa[c] = *reinterpret_cast<const float4*>(x + (size_t)r * DMODEL + c * 256 + lane * 4);

    for (int it = 0; it < ROWS_PER_WAVE; ++it) {
        const int rn = r + 4;
        const int rp = (it == ROWS_PER_WAVE - 1) ? r : rn;
        float4 xb[4];
#pragma unroll
        for (int c = 0; c < 4; ++c)
            xb[c] = *reinterpret_cast<const float4*>(x + (size_t)rp * DMODEL + c * 256 + lane * 4);

        // --- per-lane accumulate (all f32; error << MARGIN, see header) ---
        float s = 0.0f, qq = 0.0f;
        float A[NL];
#pragma unroll
        for (int n = 0; n < NL; ++n) A[n] = 0.0f;

#pragma unroll
        for (int c = 0; c < 4; ++c) {
            const float x0 = xa[c].x, x1 = xa[c].y, x2 = xa[c].z, x3 = xa[c].w;
            s += x0 + x1 + x2 + x3;
            qq = fmaf(x0, x0, qq); qq = fmaf(x1, x1, qq);
            qq = fmaf(x2, x2, qq); qq = fmaf(x3, x3, qq);
#pragma unroll
            for (int n = 0; n < NL; ++n) {
                A[n] = fmaf(x0, gw[n][c].x, A[n]);
                A[n] = fmaf(x1, gw[n][c].y, A[n]);
                A[n] = fmaf(x2, gw[n][c].z, A[n]);
                A[n] = fmaf(x3, gw[n][c].w, A[n]);
            }
        }

#pragma unroll
        for (int m = 32; m >= 1; m >>= 1) {
            s  += __shfl_xor(s,  m, 64);
            qq += __shfl_xor(qq, m, 64);
        }
        const float S1 = reduce_scatter8_f32(A, lane);

        const float mu    = s * (1.0f / 1024.0f);
        const float var   = fmaf(-mu, mu, qq * (1.0f / 1024.0f));
        const float rstd  = rsqrtf(var + 1e-5f);
        const float logit = fmaf(rstd, fmaf(-mu, S2f, S1), S3f);

        // fast f32 tanh: t = (1-e)/(1+e), e = exp(-2|logit|); abs err ~1e-6
        const float af  = fabsf(logit);
        const float e   = __expf(-2.0f * af);
        const float t   = __fdividef(1.0f - e, 1.0f + e);
        const float b4  = copysignf(4.0f * t, logit);

        const float fr    = b4 - floorf(b4);
        const float delta = fabsf(fr - 0.5f);
        const unsigned long long near_mask = __ballot(delta < MARGIN);

        if (near_mask == 0ull) {
            if ((lane & 7) == 0)
                out[(size_t)r * NL + nidx] = rintf(b4);
        } else {
            // ======== fixup: bit-exact numpy-f32 replication ========
            float* xr = &xbuf[wv][0];
#pragma unroll
            for (int c = 0; c < 4; ++c)
                *reinterpret_cast<float4*>(xr + c * 256 + lane * 4) = xa[c];
            __threadfence_block();   // drain ds_writes before cross-lane reads

            // mean: pairwise f32, /1024 exact
            const float sum32 = np_pairwise_sum_sq(xr, lane, 0.0f, 0);
            const float mu32  = __fmul_rn(sum32, 0.0009765625f);
            // var: pairwise f32 over (x-mu)^2, /1024 exact
            const float sq32  = np_pairwise_sum_sq(xr, lane, mu32, 1);
            const float var32 = __fmul_rn(sq32, 0.0009765625f);
            const float rstd32 = __fdiv_rn(1.0f, __fsqrt_rn(__fadd_rn(var32, 1e-5f)));

            // einsum dot, SSE3 baseline c_einsum: width 4, no fma,
            // 16 elems/iter, serpentine j=3..0, finale (v0+v1)+(v2+v3).
            if (lane < 32) {
                const int n = lane >> 2, v = lane & 3;
                const float* Wn = W + n * DMODEL;
                float vacc = 0.0f;
                for (int i = 0; i < DMODEL; i += 16) {
#pragma unroll
                    for (int j = 3; j >= 0; --j) {
                        const int e2 = i + 4 * j + v;
                        const float t1 = __fsub_rn(xr[e2], mu32);
                        const float t2 = __fmul_rn(t1, rstd32);
                        const float t3 = __fmul_rn(t2, gamma[e2]);
                        const float h  = __fadd_rn(t3, beta[e2]);
                        vacc = __fadd_rn(__fmul_rn(h, Wn[e2]), vacc);
                    }
                }
                float s01 = __fadd_rn(vacc, __shfl_xor(vacc, 1, 64));
                float lg  = __fadd_rn(s01,  __shfl_xor(s01, 2, 64));
                if (v == 0) {
                    const double y = 4.0 * tanh((double)lg);
                    out[(size_t)r * NL + n] = (float)rint(y);
                }
            }
        }

#pragma unroll
        for (int c = 0; c < 4; ++c) xa[c] = xb[c];
        r = rn;
    }
}

extern "C" void kernel_launch(void* const* d_in, const int* in_sizes, int n_in,
                              void* d_out, int out_size, void* d_ws, size_t ws_size,
                              hipStream_t stream) {
    const float* regrs = (const float*)d_in[0];
    const float* gamma = (const float*)d_in[1];
    const float* beta  = (const float*)d_in[2];
    const float* W     = (const float*)d_in[3];
    float* out = (float*)d_out;
    (void)in_sizes; (void)n_in; (void)out_size; (void)d_ws; (void)ws_size;

    fsq_kernel<<<NBLOCKS, TPB, 0, stream>>>(regrs, gamma, beta, W, out);
}

// Round 8
// 399.550 us; speedup vs baseline: 1.7317x; 1.0045x over previous
//
#include <hip/hip_runtime.h>
#include <math.h>

// FSQ: h = LayerNorm(x); logits = h @ W^T (n=8); q = round(4*tanh(logits))
// rows = 65536, D = 1024. Memory-bound (256 MiB read), roofline ~43 us.
//
// Fast path: all-f32, register-resident gw = gamma*W (128 f32 regs).
//   Per lane: 16 x-elements, A[n] += x*gw (8 accumulators), tree-reduced
//   across 64 lanes -> f32 dot error ~1e-5, far under MARGIN. mean/var f32
//   (E[x^2]-mu^2), tanh via f32 exp. Rows with 4*tanh within MARGIN of a
//   rounding boundary (~2%) take a fixup that replicates numpy-f32
//   semantics bit-exactly (LDS-staged row).
//
// ALLOCATOR MODEL (hard-won): on this toolchain the backend allocates
// VGPRs at cap = 256 / launch_bounds_arg2 (equivalently 512/(2N)) and
// SPILLS whatever is live beyond that, rather than dropping occupancy:
//   (256,2) -> 128 alloc (r0 fp64: ~260 live, 1.24 GB spill FETCH)
//   (256,4)/waves_per_eu(4,4) -> 64 alloc (r3/r4: 175-239 MB scratch)
// r2/r5/r6 (~190 live f32 under (256,2)) were therefore ALSO spill-bound
// (~60 regs/lane/iter -> ~4x traffic ~ 1 GB ~ 150 us), which explains the
// measured invariance to occupancy (r5) and row mapping (r6): spill BW
// scales with work, not waves. This rev: __launch_bounds__(256,1) ->
// 256-VGPR cap, ~190 live fits, zero spill. 8 waves/CU + 4KB/wave
// prefetch in flight keeps HBM the binding resource.
//
// Rev history: r0 920us (fp64+spill) / r2 157 (f32, hidden spill) /
// r3 365, r4 438 (LDS-gw, allocator spilled at 64 VGPR) / r5 157 (2x
// occupancy, null) / r6 151 (contiguous mapping, null) / r7: infra
// failure (container), identical source resubmitted.

#define NROWS 65536
#define DMODEL 1024
#define NL 8
#define NBLOCKS 1024
#define TPB 256
#define ROWS_PER_BLOCK 64            // NROWS / NBLOCKS
#define ROWS_PER_WAVE 16             // ROWS_PER_BLOCK / 4 waves
#define MARGIN 2e-3f

// Reduce-scatter 8 doubles across 64 lanes.
// After: every lane holds total of a[n] with n = 4*bit5 + 2*bit4 + 1*bit3.
__device__ __forceinline__ double reduce_scatter8_f64(double a[8], int lane) {
#pragma unroll
    for (int i = 0; i < 4; ++i) {
        double snd = (lane & 32) ? a[i] : a[i + 4];
        double rcv = __shfl_xor(snd, 32, 64);
        double kp  = (lane & 32) ? a[i + 4] : a[i];
        a[i] = kp + rcv;
    }
#pragma unroll
    for (int i = 0; i < 2; ++i) {
        double snd = (lane & 16) ? a[i] : a[i + 2];
        double rcv = __shfl_xor(snd, 16, 64);
        double kp  = (lane & 16) ? a[i + 2] : a[i];
        a[i] = kp + rcv;
    }
    {
        double snd = (lane & 8) ? a[0] : a[1];
        double rcv = __shfl_xor(snd, 8, 64);
        double kp  = (lane & 8) ? a[1] : a[0];
        a[0] = kp + rcv;
    }
    double v = a[0];
    v += __shfl_xor(v, 4, 64);
    v += __shfl_xor(v, 2, 64);
    v += __shfl_xor(v, 1, 64);
    return v;
}

// Same, f32 (fast path).
__device__ __forceinline__ float reduce_scatter8_f32(float a[8], int lane) {
#pragma unroll
    for (int i = 0; i < 4; ++i) {
        float snd = (lane & 32) ? a[i] : a[i + 4];
        float rcv = __shfl_xor(snd, 32, 64);
        float kp  = (lane & 32) ? a[i + 4] : a[i];
        a[i] = kp + rcv;
    }
#pragma unroll
    for (int i = 0; i < 2; ++i) {
        float snd = (lane & 16) ? a[i] : a[i + 2];
        float rcv = __shfl_xor(snd, 16, 64);
        float kp  = (lane & 16) ? a[i + 2] : a[i];
        a[i] = kp + rcv;
    }
    {
        float snd = (lane & 8) ? a[0] : a[1];
        float rcv = __shfl_xor(snd, 8, 64);
        float kp  = (lane & 8) ? a[1] : a[0];
        a[0] = kp + rcv;
    }
    float v = a[0];
    v += __shfl_xor(v, 4, 64);
    v += __shfl_xor(v, 2, 64);
    v += __shfl_xor(v, 1, 64);
    return v;
}

// numpy pairwise_sum over 1024 contiguous f32 in LDS, bit-exact:
// 4 recursion levels -> 8 blocks of 128; per block 8 accumulators r[j],
// r[j] = x[j]; r[j] += x[8i+j] (i=1..15); tree ((r0+r1)+(r2+r3))+((r4+r5)+(r6+r7));
// block sums combined ((s0+s1)+(s2+s3))+((s4+s5)+(s6+s7)).
// Lane L = 8*b + j owns accumulator j of block b; butterfly masks 1,2,4,8,16,32
// reproduce both trees bit-exactly (fl(a+b)==fl(b+a) => all lanes identical).
__device__ __forceinline__ float np_pairwise_sum_sq(const float* xr, int lane,
                                                    float mu, int do_sq) {
    const int b = lane >> 3, j = lane & 7;
    const float* xb = xr + 128 * b;
    float r;
    if (do_sq) {
        float t = __fsub_rn(xb[j], mu);
        r = __fmul_rn(t, t);
        for (int i = 8; i < 128; i += 8) {
            float u = __fsub_rn(xb[i + j], mu);
            r = __fadd_rn(r, __fmul_rn(u, u));
        }
    } else {
        r = xb[j];
        for (int i = 8; i < 128; i += 8)
            r = __fadd_rn(r, xb[i + j]);
    }
    r = __fadd_rn(r, __shfl_xor(r, 1, 64));
    r = __fadd_rn(r, __shfl_xor(r, 2, 64));
    r = __fadd_rn(r, __shfl_xor(r, 4, 64));
    r = __fadd_rn(r, __shfl_xor(r, 8, 64));
    r = __fadd_rn(r, __shfl_xor(r, 16, 64));
    r = __fadd_rn(r, __shfl_xor(r, 32, 64));
    return r;   // identical on all 64 lanes
}

__global__ __launch_bounds__(TPB, 1)
void fsq_kernel(const float* __restrict__ x,
                const float* __restrict__ gamma,
                const float* __restrict__ beta,
                const float* __restrict__ W,
                float* __restrict__ out)
{
    __shared__ float xbuf[TPB / 64][DMODEL];   // 16 KiB: staged x row per wave

    const int lane = threadIdx.x & 63;
    const int wv   = threadIdx.x >> 6;

    // output column this lane's reduce-scatter group owns
    const int nidx = ((lane >> 5) & 1) * 4 + ((lane >> 4) & 1) * 2 + ((lane >> 3) & 1);

    // ---- prologue: gw = gamma*W register-resident (f32); S2/S3 in f64 ----
    float4 gw[NL][4];
    float S2f, S3f;
    {
        double s2p[NL], s3p[NL];
#pragma unroll
        for (int n = 0; n < NL; ++n) { s2p[n] = 0.0; s3p[n] = 0.0; }
#pragma unroll
        for (int c = 0; c < 4; ++c) {
            const int d = c * 256 + lane * 4;
            const float4 g = *reinterpret_cast<const float4*>(gamma + d);
            const float4 b = *reinterpret_cast<const float4*>(beta + d);
#pragma unroll
            for (int n = 0; n < NL; ++n) {
                const float4 w = *reinterpret_cast<const float4*>(W + n * DMODEL + d);
                s2p[n] = fma((double)g.x, (double)w.x, s2p[n]);
                s2p[n] = fma((double)g.y, (double)w.y, s2p[n]);
                s2p[n] = fma((double)g.z, (double)w.z, s2p[n]);
                s2p[n] = fma((double)g.w, (double)w.w, s2p[n]);
                s3p[n] = fma((double)b.x, (double)w.x, s3p[n]);
                s3p[n] = fma((double)b.y, (double)w.y, s3p[n]);
                s3p[n] = fma((double)b.z, (double)w.z, s3p[n]);
                s3p[n] = fma((double)b.w, (double)w.w, s3p[n]);
                gw[n][c] = make_float4(g.x * w.x, g.y * w.y, g.z * w.z, g.w * w.w);
            }
        }
        S2f = (float)reduce_scatter8_f64(s2p, lane);
        S3f = (float)reduce_scatter8_f64(s3p, lane);
    }

    // ------- row loop: block-contiguous rows, 4-wave interleave, prefetch -------
    int r = blockIdx.x * ROWS_PER_BLOCK + wv;   // rows r, r+4, ..., r+60
    float4 xa[4];
#pragma unroll
    for (int c = 0; c < 4; ++c)
        xa[c] = *reinterpret_cast<const float4*>(x + (size_t)r * DMODEL + c * 256 + lane * 4);

    for (int it = 0; it < ROWS_PER_WAVE; ++it) {
        const int rn = r + 4;
        const int rp = (it == ROWS_PER_WAVE - 1) ? r : rn;
        float4 xb[4];
#pragma unroll
        for (int c = 0; c < 4; ++c)
            xb[c] = *reinterpret_cast<const float4*>(x + (size_t)rp * DMODEL + c * 256 + lane * 4);

        // --- per-lane accumulate (all f32; error << MARGIN, see header) ---
        float s = 0.0f, qq = 0.0f;
        float A[NL];
#pragma unroll
        for (int n = 0; n < NL; ++n) A[n] = 0.0f;

#pragma unroll
        for (int c = 0; c < 4; ++c) {
            const float x0 = xa[c].x, x1 = xa[c].y, x2 = xa[c].z, x3 = xa[c].w;
            s += x0 + x1 + x2 + x3;
            qq = fmaf(x0, x0, qq); qq = fmaf(x1, x1, qq);
            qq = fmaf(x2, x2, qq); qq = fmaf(x3, x3, qq);
#pragma unroll
            for (int n = 0; n < NL; ++n) {
                A[n] = fmaf(x0, gw[n][c].x, A[n]);
                A[n] = fmaf(x1, gw[n][c].y, A[n]);
                A[n] = fmaf(x2, gw[n][c].z, A[n]);
                A[n] = fmaf(x3, gw[n][c].w, A[n]);
            }
        }

#pragma unroll
        for (int m = 32; m >= 1; m >>= 1) {
            s  += __shfl_xor(s,  m, 64);
            qq += __shfl_xor(qq, m, 64);
        }
        const float S1 = reduce_scatter8_f32(A, lane);

        const float mu    = s * (1.0f / 1024.0f);
        const float var   = fmaf(-mu, mu, qq * (1.0f / 1024.0f));
        const float rstd  = rsqrtf(var + 1e-5f);
        const float logit = fmaf(rstd, fmaf(-mu, S2f, S1), S3f);

        // fast f32 tanh: t = (1-e)/(1+e), e = exp(-2|logit|); abs err ~1e-6
        const float af  = fabsf(logit);
        const float e   = __expf(-2.0f * af);
        const float t   = __fdividef(1.0f - e, 1.0f + e);
        const float b4  = copysignf(4.0f * t, logit);

        const float fr    = b4 - floorf(b4);
        const float delta = fabsf(fr - 0.5f);
        const unsigned long long near_mask = __ballot(delta < MARGIN);

        if (near_mask == 0ull) {
            if ((lane & 7) == 0)
                out[(size_t)r * NL + nidx] = rintf(b4);
        } else {
            // ======== fixup: bit-exact numpy-f32 replication ========
            float* xr = &xbuf[wv][0];
#pragma unroll
            for (int c = 0; c < 4; ++c)
                *reinterpret_cast<float4*>(xr + c * 256 + lane * 4) = xa[c];
            __threadfence_block();   // drain ds_writes before cross-lane reads

            // mean: pairwise f32, /1024 exact
            const float sum32 = np_pairwise_sum_sq(xr, lane, 0.0f, 0);
            const float mu32  = __fmul_rn(sum32, 0.0009765625f);
            // var: pairwise f32 over (x-mu)^2, /1024 exact
            const float sq32  = np_pairwise_sum_sq(xr, lane, mu32, 1);
            const float var32 = __fmul_rn(sq32, 0.0009765625f);
            const float rstd32 = __fdiv_rn(1.0f, __fsqrt_rn(__fadd_rn(var32, 1e-5f)));

            // einsum dot, SSE3 baseline c_einsum: width 4, no fma,
            // 16 elems/iter, serpentine j=3..0, finale (v0+v1)+(v2+v3).
            if (lane < 32) {
                const int n = lane >> 2, v = lane & 3;
                const float* Wn = W + n * DMODEL;
                float vacc = 0.0f;
                for (int i = 0; i < DMODEL; i += 16) {
#pragma unroll
                    for (int j = 3; j >= 0; --j) {
                        const int e2 = i + 4 * j + v;
                        const float t1 = __fsub_rn(xr[e2], mu32);
                        const float t2 = __fmul_rn(t1, rstd32);
                        const float t3 = __fmul_rn(t2, gamma[e2]);
                        const float h  = __fadd_rn(t3, beta[e2]);
                        vacc = __fadd_rn(__fmul_rn(h, Wn[e2]), vacc);
                    }
                }
                float s01 = __fadd_rn(vacc, __shfl_xor(vacc, 1, 64));
                float lg  = __fadd_rn(s01,  __shfl_xor(s01, 2, 64));
                if (v == 0) {
                    const double y = 4.0 * tanh((double)lg);
                    out[(size_t)r * NL + n] = (float)rint(y);
                }
            }
        }

#pragma unroll
        for (int c = 0; c < 4; ++c) xa[c] = xb[c];
        r = rn;
    }
}

extern "C" void kernel_launch(void* const* d_in, const int* in_sizes, int n_in,
                              void* d_out, int out_size, void* d_ws, size_t ws_size,
                              hipStream_t stream) {
    const float* regrs = (const float*)d_in[0];
    const float* gamma = (const float*)d_in[1];
    const float* beta  = (const float*)d_in[2];
    const float* W     = (const float*)d_in[3];
    float* out = (float*)d_out;
    (void)in_sizes; (void)n_in; (void)out_size; (void)d_ws; (void)ws_size;

    fsq_kernel<<<NBLOCKS, TPB, 0, stream>>>(regrs, gamma, beta, W, out);
}